// Round 1
// baseline (308.240 us; speedup 1.0000x reference)
//
#include <hip/hip_runtime.h>

typedef unsigned short ushort_t;

#define M_DIM 1024   // 2*512 rows of x
#define N_DIM 4096   // OUT_F
#define K_DIM 4096   // IN_F
#define NFREQ 10000
constexpr float SCALE = 150.0f / 64.0f;   // 150 / sqrt(4096)

typedef __bf16 bf16x8_t __attribute__((ext_vector_type(8)));
typedef float  f32x4_t  __attribute__((ext_vector_type(4)));

__device__ inline ushort_t f2bf(float f) {
  union { float f; unsigned u; } v; v.f = f;
  unsigned r = v.u + 0x7fffu + ((v.u >> 16) & 1u);   // RNE
  return (ushort_t)(r >> 16);
}

// ---------------------------------------------------------------------------
// Kernel 1: W' = bf16( weight + s * iwht(scatter(spectrum, indices)) )
// ΔW[o,i] = s * Σ_{j: c_j==i} (-1)^popcount(o & r_j) * val_j   (last-j wins on dup cells)
// Each block: 64 o-rows × 64 i-cols. Scan indices once, bucket per column in LDS.
// ---------------------------------------------------------------------------
__global__ __launch_bounds__(256) void build_w(
    const float* __restrict__ weight,
    const float* __restrict__ spectrum,
    const int* __restrict__ idx,          // [2][NFREQ]: row 0 = r (out), row 1 = c (in)
    ushort_t* __restrict__ wb) {
  constexpr int CAP = 1024;
  __shared__ int   ls_r[CAP];
  __shared__ int   ls_cj[CAP];            // (dc<<14) | j
  __shared__ float ls_v[CAP];
  __shared__ int   s_r2[CAP];
  __shared__ float s_v2[CAP];
  __shared__ int   cnt;
  __shared__ int   col_start[65];
  __shared__ int   col_cnt[64];
  __shared__ int   col_off[64];

  const int tid = threadIdx.x;
  const int ci0 = blockIdx.x * 64;
  const int o0  = blockIdx.y * 64;

  if (tid == 0) cnt = 0;
  __syncthreads();

  // 1) collect matches for this column range
  for (int j = tid; j < NFREQ; j += 256) {
    int c = idx[NFREQ + j];
    if (c >= ci0 && c < ci0 + 64) {
      int p = atomicAdd(&cnt, 1);
      if (p < CAP) {
        ls_r[p]  = idx[j];
        ls_cj[p] = ((c - ci0) << 14) | j;
        ls_v[p]  = spectrum[j];
      }
    }
  }
  __syncthreads();
  int n = cnt < CAP ? cnt : CAP;

  // 2) last-wins dedup: kill entries that have a later j with same (r, c)
  for (int e = tid; e < n; e += 256) {
    int r = ls_r[e], cj = ls_cj[e];
    int dc = cj >> 14, j = cj & 16383;
    bool dead = false;
    for (int e2 = 0; e2 < n; ++e2) {
      int cj2 = ls_cj[e2];
      if ((cj2 >> 14) == dc && (cj2 & 16383) > j && ls_r[e2] == r) dead = true;
    }
    if (dead) ls_v[e] = 0.0f;             // additive no-op == excluded
  }

  // 3) counting sort by column
  if (tid < 64) col_cnt[tid] = 0;
  __syncthreads();
  for (int e = tid; e < n; e += 256) atomicAdd(&col_cnt[ls_cj[e] >> 14], 1);
  __syncthreads();
  if (tid == 0) {
    int s = 0;
    for (int c = 0; c < 64; ++c) { col_start[c] = s; s += col_cnt[c]; }
    col_start[64] = s;
  }
  __syncthreads();
  if (tid < 64) col_off[tid] = col_start[tid];
  __syncthreads();
  for (int e = tid; e < n; e += 256) {
    int dc = ls_cj[e] >> 14;
    int p = atomicAdd(&col_off[dc], 1);
    s_r2[p] = ls_r[e];
    s_v2[p] = ls_v[e];
  }
  __syncthreads();

  // 4) evaluate tile: consecutive tid -> consecutive i (coalesced)
  for (int t = tid; t < 64 * 64; t += 256) {
    int dr = t >> 6, dc = t & 63;
    int o = o0 + dr;
    float acc = 0.0f;
    for (int p = col_start[dc]; p < col_start[dc + 1]; ++p) {
      float v = s_v2[p];
      acc += (__popc(o & s_r2[p]) & 1) ? -v : v;
    }
    size_t g = (size_t)o * K_DIM + ci0 + dc;
    wb[g] = f2bf(weight[g] + SCALE * acc);
  }
}

// ---------------------------------------------------------------------------
// Kernel 2: x fp32 -> bf16
// ---------------------------------------------------------------------------
__global__ __launch_bounds__(256) void cvt_x(const float* __restrict__ x,
                                             ushort_t* __restrict__ xb) {
  int i = blockIdx.x * 256 + threadIdx.x;   // one float4 per thread; grid covers exactly
  float4 v = ((const float4*)x)[i];
  ushort4 o;
  o.x = f2bf(v.x); o.y = f2bf(v.y); o.z = f2bf(v.z); o.w = f2bf(v.w);
  ((ushort4*)xb)[i] = o;
}

// ---------------------------------------------------------------------------
// Kernel 3: C[M,N] = A[M,K] * B[N,K]^T   (bf16 in, fp32 out)
// 128x128x32 tile, global_load_lds(16B) staging, mfma_f32_16x16x32_bf16.
// ---------------------------------------------------------------------------
__global__ __launch_bounds__(256) void gemm_bt(
    const ushort_t* __restrict__ A,   // xb [M,K]
    const ushort_t* __restrict__ B,   // wb [N,K]
    float* __restrict__ C) {
  constexpr int BM = 128, BN = 128, BK = 32;
  __shared__ __align__(16) ushort_t As[BM * BK];   // row-major [row][k], 8 KB
  __shared__ __align__(16) ushort_t Bs[BN * BK];

  const int tid  = threadIdx.x;
  const int wave = tid >> 6, lane = tid & 63;
  const int wrow = wave >> 1, wcol = wave & 1;     // 2x2 waves, 64x64 each
  const int l16  = lane & 15, quad = lane >> 4;
  const int bm = blockIdx.y * BM, bn = blockIdx.x * BN;

  // staging geometry: 8 chunks of 1KB per matrix; chunk = 16 rows; lane -> row/k
  const int srow = lane >> 2;            // 0..15 within chunk
  const int skof = (lane & 3) * 8;       // k offset (elements)

  f32x4_t acc[4][4] = {};

  for (int kt = 0; kt < K_DIM; kt += BK) {
    for (int c2 = 0; c2 < 2; ++c2) {
      int chunk = wave * 2 + c2;                  // wave-uniform
      int row = chunk * 16 + srow;
      const ushort_t* ga = A + (size_t)(bm + row) * K_DIM + kt + skof;
      __builtin_amdgcn_global_load_lds(
          (const __attribute__((address_space(1))) void*)ga,
          (__attribute__((address_space(3))) void*)&As[chunk * 512], 16, 0, 0);
      const ushort_t* gb = B + (size_t)(bn + row) * K_DIM + kt + skof;
      __builtin_amdgcn_global_load_lds(
          (const __attribute__((address_space(1))) void*)gb,
          (__attribute__((address_space(3))) void*)&Bs[chunk * 512], 16, 0, 0);
    }
    __syncthreads();   // drains vmcnt -> LDS tile visible

    bf16x8_t af[4], bfr[4];
#pragma unroll
    for (int i = 0; i < 4; ++i) {
      int arow = wrow * 64 + i * 16 + l16;
      af[i] = *(const bf16x8_t*)&As[arow * BK + quad * 8];
      int brow = wcol * 64 + i * 16 + l16;
      bfr[i] = *(const bf16x8_t*)&Bs[brow * BK + quad * 8];
    }
#pragma unroll
    for (int i = 0; i < 4; ++i)
#pragma unroll
      for (int j = 0; j < 4; ++j)
        acc[i][j] = __builtin_amdgcn_mfma_f32_16x16x32_bf16(af[i], bfr[j], acc[i][j], 0, 0, 0);
    __syncthreads();   // before overwriting LDS next iter
  }

  // epilogue: C/D layout col = lane&15 (n side), row = quad*4 + reg (m side)
#pragma unroll
  for (int i = 0; i < 4; ++i) {
#pragma unroll
    for (int j = 0; j < 4; ++j) {
      int col = bn + wcol * 64 + j * 16 + l16;
#pragma unroll
      for (int r = 0; r < 4; ++r) {
        int row = bm + wrow * 64 + i * 16 + quad * 4 + r;
        C[(size_t)row * N_DIM + col] = acc[i][j][r];
      }
    }
  }
}

extern "C" void kernel_launch(void* const* d_in, const int* in_sizes, int n_in,
                              void* d_out, int out_size, void* d_ws, size_t ws_size,
                              hipStream_t stream) {
  const float* x        = (const float*)d_in[0];   // [2,512,4096]
  const float* weight   = (const float*)d_in[1];   // [4096,4096]
  const float* spectrum = (const float*)d_in[2];   // [10000]
  const int*   indices  = (const int*)d_in[3];     // [2,10000]
  float* out = (float*)d_out;                      // [2,512,4096]

  ushort_t* wb = (ushort_t*)d_ws;                                          // 32 MB
  ushort_t* xb = (ushort_t*)((char*)d_ws + (size_t)N_DIM * K_DIM * 2);     // +8 MB

  build_w<<<dim3(64, 64), 256, 0, stream>>>(weight, spectrum, indices, wb);
  cvt_x<<<(M_DIM * K_DIM / 4) / 256, 256, 0, stream>>>(x, xb);
  gemm_bt<<<dim3(N_DIM / 128, M_DIM / 128), 256, 0, stream>>>(xb, wb, out);
}

// Round 2
// 287.209 us; speedup vs baseline: 1.0732x; 1.0732x over previous
//
#include <hip/hip_runtime.h>

typedef unsigned short ushort_t;

#define M_DIM 1024   // 2*512 rows of x
#define N_DIM 4096   // OUT_F
#define K_DIM 4096   // IN_F
#define NFREQ 10000
constexpr float SCALE = 150.0f / 64.0f;   // 150 / sqrt(4096)

typedef __bf16 bf16x8_t __attribute__((ext_vector_type(8)));
typedef float  f32x4_t  __attribute__((ext_vector_type(4)));

__device__ inline ushort_t f2bf(float f) {
  union { float f; unsigned u; } v; v.f = f;
  unsigned r = v.u + 0x7fffu + ((v.u >> 16) & 1u);   // RNE
  return (ushort_t)(r >> 16);
}

// ---------------------------------------------------------------------------
// Kernel 0: prep — bucket the 10000 (r,c,v) triplets by column c into a global
// CSR structure (col_ptr[4097], ent_jr[10000] = (j<<12)|r, ent_v[10000]),
// with last-write-wins dedup applied ONCE (earlier-j duplicate of same (r,c)
// gets v=0, an additive no-op). Single block, 1024 threads.
// ---------------------------------------------------------------------------
__global__ __launch_bounds__(1024) void prep(
    const int* __restrict__ idx,          // [2][NFREQ]: row 0 = r (out), row 1 = c (in)
    const float* __restrict__ spectrum,
    int* __restrict__ col_ptr,            // [4097]
    int* __restrict__ ent_jr,             // [NFREQ]
    float* __restrict__ ent_v) {          // [NFREQ]
  __shared__ int cnt[4096];
  __shared__ int base[4096];
  __shared__ int wsum[16];
  const int tid = threadIdx.x;

  for (int c = tid; c < 4096; c += 1024) cnt[c] = 0;
  __syncthreads();
  for (int j = tid; j < NFREQ; j += 1024) atomicAdd(&cnt[idx[NFREQ + j]], 1);
  __syncthreads();

  // exclusive prefix sum over 4096 counts: 4 per thread + wave scan + serial wave-sum scan
  const int c0 = tid * 4;
  int a0 = cnt[c0], a1 = cnt[c0 + 1], a2 = cnt[c0 + 2], a3 = cnt[c0 + 3];
  int s = a0 + a1 + a2 + a3;
  const int lane = tid & 63, wv = tid >> 6;
  int v = s;
  for (int d = 1; d < 64; d <<= 1) {
    int o = __shfl_up(v, d, 64);
    if (lane >= d) v += o;
  }
  if (lane == 63) wsum[wv] = v;
  __syncthreads();
  if (tid == 0) {
    int acc = 0;
    for (int w = 0; w < 16; ++w) { int t = wsum[w]; wsum[w] = acc; acc += t; }
  }
  __syncthreads();
  int excl = v - s + wsum[wv];
  base[c0]     = excl;
  base[c0 + 1] = excl + a0;
  base[c0 + 2] = excl + a0 + a1;
  base[c0 + 3] = excl + a0 + a1 + a2;
  col_ptr[c0]     = base[c0];
  col_ptr[c0 + 1] = base[c0 + 1];
  col_ptr[c0 + 2] = base[c0 + 2];
  col_ptr[c0 + 3] = base[c0 + 3];
  if (tid == 1023) col_ptr[4096] = excl + s;   // == NFREQ
  __syncthreads();

  // scatter into buckets (order within bucket arbitrary; j carried for dedup)
  for (int j = tid; j < NFREQ; j += 1024) {
    int c = idx[NFREQ + j], r = idx[j];
    int p = atomicAdd(&base[c], 1);
    ent_jr[p] = (j << 12) | r;        // r in [0,4096) fits 12 bits; j<10000 fits above
    ent_v[p]  = spectrum[j];
  }
  __syncthreads();   // block-level fence: global writes visible to whole block

  // per-column last-wins dedup: zero v of entries shadowed by a later j, same r
  for (int c = tid; c < 4096; c += 1024) {
    int e = base[c];           // == end of bucket c after scatter
    int s0 = e - cnt[c];
    for (int p1 = s0; p1 < e; ++p1) {
      int jr1 = ent_jr[p1];
      int r1 = jr1 & 0xFFF, j1 = jr1 >> 12;
      bool dead = false;
      for (int p2 = s0; p2 < e; ++p2) {
        if (p2 == p1) continue;
        int jr2 = ent_jr[p2];
        if ((jr2 & 0xFFF) == r1 && (jr2 >> 12) > j1) dead = true;
      }
      if (dead) ent_v[p1] = 0.0f;
    }
  }
}

// ---------------------------------------------------------------------------
// Kernel 1: W' = bf16( weight + s * iwht(dense) ) using the CSR buckets.
// Block: 64 i-cols x 256 o-rows. Thread: 4 consecutive cols, 16 row-passes.
// ---------------------------------------------------------------------------
__global__ __launch_bounds__(256) void build_w2(
    const float* __restrict__ weight,
    const int* __restrict__ col_ptr,
    const int* __restrict__ ent_jr,
    const float* __restrict__ ent_v,
    ushort_t* __restrict__ wb) {
  constexpr int CAP = 1024;
  __shared__ int   ls_ptr[65];
  __shared__ int   ls_jr[CAP];
  __shared__ float ls_v[CAP];

  const int tid = threadIdx.x;
  const int ci0 = blockIdx.x * 64;
  const int o0  = blockIdx.y * 256;

  if (tid < 65) ls_ptr[tid] = col_ptr[ci0 + tid];
  __syncthreads();
  const int ebase = ls_ptr[0];
  const int nloc  = ls_ptr[64] - ebase;
  const bool lds_ok = (nloc <= CAP);
  if (lds_ok) {
    for (int e = tid; e < nloc; e += 256) {
      ls_jr[e] = ent_jr[ebase + e];
      ls_v[e]  = ent_v[ebase + e];
    }
  }
  __syncthreads();
  const int*   jr = lds_ok ? (const int*)ls_jr   : (ent_jr + ebase);
  const float* vv = lds_ok ? (const float*)ls_v  : (ent_v + ebase);

  const int dc0 = (tid & 15) * 4;
  const int rof = tid >> 4;
  int s0 = ls_ptr[dc0]     - ebase, e0 = ls_ptr[dc0 + 1] - ebase;
  int s1 = ls_ptr[dc0 + 1] - ebase, e1 = ls_ptr[dc0 + 2] - ebase;
  int s2 = ls_ptr[dc0 + 2] - ebase, e2 = ls_ptr[dc0 + 3] - ebase;
  int s3 = ls_ptr[dc0 + 3] - ebase, e3 = ls_ptr[dc0 + 4] - ebase;

  for (int pass = 0; pass < 16; ++pass) {
    int o = o0 + pass * 16 + rof;
    size_t g = (size_t)o * K_DIM + ci0 + dc0;
    float4 w4 = *(const float4*)&weight[g];
    float a0 = 0.f, a1 = 0.f, a2 = 0.f, a3 = 0.f;
    for (int p = s0; p < e0; ++p) { float v = vv[p]; a0 += (__popc(o & (jr[p] & 0xFFF)) & 1) ? -v : v; }
    for (int p = s1; p < e1; ++p) { float v = vv[p]; a1 += (__popc(o & (jr[p] & 0xFFF)) & 1) ? -v : v; }
    for (int p = s2; p < e2; ++p) { float v = vv[p]; a2 += (__popc(o & (jr[p] & 0xFFF)) & 1) ? -v : v; }
    for (int p = s3; p < e3; ++p) { float v = vv[p]; a3 += (__popc(o & (jr[p] & 0xFFF)) & 1) ? -v : v; }
    ushort4 ov;
    ov.x = f2bf(w4.x + SCALE * a0);
    ov.y = f2bf(w4.y + SCALE * a1);
    ov.z = f2bf(w4.z + SCALE * a2);
    ov.w = f2bf(w4.w + SCALE * a3);
    *(ushort4*)&wb[g] = ov;
  }
}

// ---------------------------------------------------------------------------
// Kernel 2: x fp32 -> bf16
// ---------------------------------------------------------------------------
__global__ __launch_bounds__(256) void cvt_x(const float* __restrict__ x,
                                             ushort_t* __restrict__ xb) {
  int i = blockIdx.x * 256 + threadIdx.x;
  float4 v = ((const float4*)x)[i];
  ushort4 o;
  o.x = f2bf(v.x); o.y = f2bf(v.y); o.z = f2bf(v.z); o.w = f2bf(v.w);
  ((ushort4*)xb)[i] = o;
}

// ---------------------------------------------------------------------------
// Kernel 3: C[M,N] = A[M,K] * B[N,K]^T  (bf16 in, fp32 out), split-K via z.
// 128x128 tile, BK=32, global_load_lds(16B), mfma_f32_16x16x32_bf16.
// z-chunk 0 writes C0, z-chunk 1 writes C1 (partial), klen per chunk.
// ---------------------------------------------------------------------------
__global__ __launch_bounds__(256) void gemm_bt(
    const ushort_t* __restrict__ A,   // xb [M,K]
    const ushort_t* __restrict__ B,   // wb [N,K]
    float* __restrict__ C0,
    float* __restrict__ C1,
    int klen) {
  constexpr int BM = 128, BN = 128, BK = 32;
  __shared__ __align__(16) ushort_t As[BM * BK];
  __shared__ __align__(16) ushort_t Bs[BN * BK];

  const int tid  = threadIdx.x;
  const int wave = tid >> 6, lane = tid & 63;
  const int wrow = wave >> 1, wcol = wave & 1;
  const int l16  = lane & 15, quad = lane >> 4;
  const int bm = blockIdx.y * BM, bn = blockIdx.x * BN;
  const int kbeg = blockIdx.z * klen;
  float* __restrict__ dst = blockIdx.z ? C1 : C0;

  const int srow = lane >> 2;
  const int skof = (lane & 3) * 8;

  f32x4_t acc[4][4] = {};

  for (int kt = kbeg; kt < kbeg + klen; kt += BK) {
    for (int c2 = 0; c2 < 2; ++c2) {
      int chunk = wave * 2 + c2;
      int row = chunk * 16 + srow;
      const ushort_t* ga = A + (size_t)(bm + row) * K_DIM + kt + skof;
      __builtin_amdgcn_global_load_lds(
          (const __attribute__((address_space(1))) void*)ga,
          (__attribute__((address_space(3))) void*)&As[chunk * 512], 16, 0, 0);
      const ushort_t* gb = B + (size_t)(bn + row) * K_DIM + kt + skof;
      __builtin_amdgcn_global_load_lds(
          (const __attribute__((address_space(1))) void*)gb,
          (__attribute__((address_space(3))) void*)&Bs[chunk * 512], 16, 0, 0);
    }
    __syncthreads();

    bf16x8_t af[4], bfr[4];
#pragma unroll
    for (int i = 0; i < 4; ++i) {
      int arow = wrow * 64 + i * 16 + l16;
      af[i] = *(const bf16x8_t*)&As[arow * BK + quad * 8];
      int brow = wcol * 64 + i * 16 + l16;
      bfr[i] = *(const bf16x8_t*)&Bs[brow * BK + quad * 8];
    }
#pragma unroll
    for (int i = 0; i < 4; ++i)
#pragma unroll
      for (int j = 0; j < 4; ++j)
        acc[i][j] = __builtin_amdgcn_mfma_f32_16x16x32_bf16(af[i], bfr[j], acc[i][j], 0, 0, 0);
    __syncthreads();
  }

#pragma unroll
  for (int i = 0; i < 4; ++i) {
#pragma unroll
    for (int j = 0; j < 4; ++j) {
      int col = bn + wcol * 64 + j * 16 + l16;
#pragma unroll
      for (int r = 0; r < 4; ++r) {
        int row = bm + wrow * 64 + i * 16 + quad * 4 + r;
        dst[(size_t)row * N_DIM + col] = acc[i][j][r];
      }
    }
  }
}

// ---------------------------------------------------------------------------
// Kernel 4: out += partial (float4)
// ---------------------------------------------------------------------------
__global__ __launch_bounds__(256) void add_partial(float* __restrict__ out,
                                                   const float* __restrict__ part) {
  int i = blockIdx.x * 256 + threadIdx.x;
  float4 a = ((const float4*)out)[i];
  float4 b = ((const float4*)part)[i];
  a.x += b.x; a.y += b.y; a.z += b.z; a.w += b.w;
  ((float4*)out)[i] = a;
}

extern "C" void kernel_launch(void* const* d_in, const int* in_sizes, int n_in,
                              void* d_out, int out_size, void* d_ws, size_t ws_size,
                              hipStream_t stream) {
  const float* x        = (const float*)d_in[0];   // [2,512,4096]
  const float* weight   = (const float*)d_in[1];   // [4096,4096]
  const float* spectrum = (const float*)d_in[2];   // [10000]
  const int*   indices  = (const int*)d_in[3];     // [2,10000]
  float* out = (float*)d_out;                      // [2,512,4096]

  char* ws = (char*)d_ws;
  const size_t WB_BYTES   = (size_t)N_DIM * K_DIM * 2;   // 32 MB
  const size_t XB_BYTES   = (size_t)M_DIM * K_DIM * 2;   //  8 MB
  const size_t PART_BYTES = (size_t)M_DIM * N_DIM * 4;   // 16 MB
  const size_t CSR_BYTES  = 4097 * 4 + NFREQ * 8 + 64;

  ushort_t* wb = (ushort_t*)ws;
  ushort_t* xb = (ushort_t*)(ws + WB_BYTES);
  const bool split = ws_size >= WB_BYTES + XB_BYTES + PART_BYTES + CSR_BYTES;
  float* part = (float*)(ws + WB_BYTES + XB_BYTES);
  char* csr = ws + WB_BYTES + XB_BYTES + (split ? PART_BYTES : 0);
  int*   col_ptr = (int*)csr;
  int*   ent_jr  = (int*)(csr + 4097 * 4 + 28);   // keep 4B-aligned
  float* ent_v   = (float*)(csr + 4097 * 4 + 28 + NFREQ * 4);

  prep<<<1, 1024, 0, stream>>>(indices, spectrum, col_ptr, ent_jr, ent_v);
  build_w2<<<dim3(K_DIM / 64, N_DIM / 256), 256, 0, stream>>>(weight, col_ptr, ent_jr, ent_v, wb);
  cvt_x<<<(M_DIM * K_DIM / 4) / 256, 256, 0, stream>>>(x, xb);

  if (split) {
    gemm_bt<<<dim3(N_DIM / 128, M_DIM / 128, 2), 256, 0, stream>>>(xb, wb, out, part, K_DIM / 2);
    add_partial<<<(M_DIM * N_DIM / 4) / 256, 256, 0, stream>>>(out, part);
  } else {
    gemm_bt<<<dim3(N_DIM / 128, M_DIM / 128, 1), 256, 0, stream>>>(xb, wb, out, out, K_DIM);
  }
}

// Round 3
// 203.581 us; speedup vs baseline: 1.5141x; 1.4108x over previous
//
#include <hip/hip_runtime.h>

typedef unsigned short ushort_t;

#define M_DIM 1024   // 2*512 rows of x
#define N_DIM 4096   // OUT_F
#define K_DIM 4096   // IN_F
#define NFREQ 10000
constexpr float SCALE = 150.0f / 64.0f;   // 150 / sqrt(4096)

typedef __bf16 bf16x8_t __attribute__((ext_vector_type(8)));
typedef float  f32x4_t  __attribute__((ext_vector_type(4)));

__device__ inline ushort_t f2bf(float f) {
  union { float f; unsigned u; } v; v.f = f;
  unsigned r = v.u + 0x7fffu + ((v.u >> 16) & 1u);   // RNE
  return (ushort_t)(r >> 16);
}

// ---------------------------------------------------------------------------
// Kernel 1: W' = bf16( weight + s * iwht(scatter(spectrum, indices)) )
// ΔW[o,i] = s * Σ_{j: c_j==i} (-1)^popcount(o & r_j) * val_j (last-j wins dup).
// Self-contained: each block scans the 10000 triplets for its 64-column group,
// counting-sorts by column in LDS, dedups in LDS, then evaluates
// 256 o-rows x 64 i-cols with float4/ushort4 traffic.
// ---------------------------------------------------------------------------
__global__ __launch_bounds__(256) void build_w3(
    const float* __restrict__ weight,
    const float* __restrict__ spectrum,
    const int* __restrict__ idx,          // [2][NFREQ]: row 0 = r (out), row 1 = c (in)
    ushort_t* __restrict__ wb) {
  constexpr int CAP = 1024;
  __shared__ unsigned e_raw[CAP];   // (dc<<26)|(j<<12)|r
  __shared__ float    v_raw[CAP];
  __shared__ unsigned e_srt[CAP];   // same pack, sorted by dc
  __shared__ float    v_srt[CAP];
  __shared__ int cnt;
  __shared__ int cstart[65];
  __shared__ int coff[64];
  __shared__ int ccnt[64];

  const int tid = threadIdx.x;
  const int ci0 = blockIdx.x * 64;
  const int o0  = blockIdx.y * 256;

  if (tid == 0) cnt = 0;
  if (tid < 64) ccnt[tid] = 0;
  __syncthreads();

  // Phase 1: collect this group's entries
  for (int j = tid; j < NFREQ; j += 256) {
    int c = idx[NFREQ + j];
    if ((c >> 6) == (int)blockIdx.x) {
      int p = atomicAdd(&cnt, 1);
      if (p < CAP) {
        e_raw[p] = ((unsigned)(c & 63) << 26) | ((unsigned)j << 12) | (unsigned)idx[j];
        v_raw[p] = spectrum[j];
        atomicAdd(&ccnt[c & 63], 1);
      }
    }
  }
  __syncthreads();
  const int n = cnt < CAP ? cnt : CAP;

  // Phase 2: prefix sum over 64 column counts (wave 0), then scatter sorted
  if (tid < 64) {
    int v = ccnt[tid];
    int s = v;
    for (int d = 1; d < 64; d <<= 1) {
      int o = __shfl_up(s, d, 64);
      if (tid >= d) s += o;
    }
    cstart[tid + 1] = s;
    if (tid == 0) cstart[0] = 0;
    coff[tid] = s - v;   // exclusive
  }
  __syncthreads();
  for (int e = tid; e < n; e += 256) {
    unsigned w = e_raw[e];
    int dc = w >> 26;
    int p = atomicAdd(&coff[dc], 1);
    e_srt[p] = w;
    v_srt[p] = v_raw[e];
  }
  __syncthreads();

  // Phase 3: last-wins dedup within each column bucket (LDS-local)
  for (int e = tid; e < n; e += 256) {
    unsigned w = e_srt[e];
    int dc = w >> 26;
    unsigned r = w & 0xFFFu, j = (w >> 12) & 0x3FFFu;
    int s0 = cstart[dc], e0 = cstart[dc + 1];
    bool dead = false;
    for (int p = s0; p < e0; ++p) {
      unsigned w2 = e_srt[p];
      if ((w2 & 0xFFFu) == r && ((w2 >> 12) & 0x3FFFu) > j) dead = true;
    }
    if (dead) v_srt[e] = 0.0f;   // additive no-op == excluded
  }
  __syncthreads();

  // Phase 4: evaluate 256x64 tile; thread = 4 consecutive cols x 16 row-passes
  const int dc0 = (tid & 15) * 4;
  const int rof = tid >> 4;
  const int s0 = cstart[dc0],     e0 = cstart[dc0 + 1];
  const int s1 = cstart[dc0 + 1], e1 = cstart[dc0 + 2];
  const int s2 = cstart[dc0 + 2], e2 = cstart[dc0 + 3];
  const int s3 = cstart[dc0 + 3], e3 = cstart[dc0 + 4];

  size_t g = (size_t)(o0 + rof) * K_DIM + ci0 + dc0;
  float4 w4 = *(const float4*)&weight[g];
  for (int pass = 0; pass < 16; ++pass) {
    size_t gn = g + (size_t)16 * K_DIM;
    float4 wnext;
    if (pass < 15) wnext = *(const float4*)&weight[gn];
    int o = o0 + pass * 16 + rof;
    float a0 = 0.f, a1 = 0.f, a2 = 0.f, a3 = 0.f;
    for (int p = s0; p < e0; ++p) { float v = v_srt[p]; a0 += (__popc(o & (e_srt[p] & 0xFFFu)) & 1) ? -v : v; }
    for (int p = s1; p < e1; ++p) { float v = v_srt[p]; a1 += (__popc(o & (e_srt[p] & 0xFFFu)) & 1) ? -v : v; }
    for (int p = s2; p < e2; ++p) { float v = v_srt[p]; a2 += (__popc(o & (e_srt[p] & 0xFFFu)) & 1) ? -v : v; }
    for (int p = s3; p < e3; ++p) { float v = v_srt[p]; a3 += (__popc(o & (e_srt[p] & 0xFFFu)) & 1) ? -v : v; }
    ushort4 ov;
    ov.x = f2bf(w4.x + SCALE * a0);
    ov.y = f2bf(w4.y + SCALE * a1);
    ov.z = f2bf(w4.z + SCALE * a2);
    ov.w = f2bf(w4.w + SCALE * a3);
    *(ushort4*)&wb[g] = ov;
    w4 = wnext;
    g = gn;
  }
}

// ---------------------------------------------------------------------------
// Kernel 2: x fp32 -> bf16
// ---------------------------------------------------------------------------
__global__ __launch_bounds__(256) void cvt_x(const float* __restrict__ x,
                                             ushort_t* __restrict__ xb) {
  int i = blockIdx.x * 256 + threadIdx.x;
  float4 v = ((const float4*)x)[i];
  ushort4 o;
  o.x = f2bf(v.x); o.y = f2bf(v.y); o.z = f2bf(v.z); o.w = f2bf(v.w);
  ((ushort4*)xb)[i] = o;
}

// ---------------------------------------------------------------------------
// Kernel 3: C[M,N] = A[M,K] * B[N,K]^T  (bf16 in, fp32 out), split-K via z.
// 128x128 tile, BK=64, XOR-swizzled LDS (conflict-free ds_read_b128),
// global_load_lds(16B) staging, mfma_f32_16x16x32_bf16, 32 MFMA per barrier.
// LDS layout: element (row, q*8+t) lives at row*64 + (q^(row&7))*8 + t.
// ---------------------------------------------------------------------------
__global__ __launch_bounds__(256) void gemm_bt(
    const ushort_t* __restrict__ A,   // xb [M,K]
    const ushort_t* __restrict__ B,   // wb [N,K]
    float* __restrict__ C0,
    float* __restrict__ C1,
    int klen) {
  constexpr int BM = 128, BN = 128, BK = 64;
  __shared__ __align__(16) ushort_t As[BM * BK];   // 16 KB
  __shared__ __align__(16) ushort_t Bs[BN * BK];   // 16 KB

  const int tid  = threadIdx.x;
  const int wave = tid >> 6, lane = tid & 63;
  const int wrow = wave >> 1, wcol = wave & 1;
  const int l16  = lane & 15, quad = lane >> 4;
  const int bm = blockIdx.y * BM, bn = blockIdx.x * BN;
  const int kbeg = blockIdx.z * klen;
  float* __restrict__ dst = blockIdx.z ? C1 : C0;

  // staging: 16 chunks of 1KB per matrix; wave does chunks wave*4..wave*4+3
  const int srow8 = lane >> 3;          // row within chunk, 0..7
  const int sq    = lane & 7;           // 16B slot within row, 0..7

  f32x4_t acc[4][4] = {};

  for (int kt = kbeg; kt < kbeg + klen; kt += BK) {
#pragma unroll
    for (int c = 0; c < 4; ++c) {
      int ch = wave * 4 + c;            // wave-uniform
      int gr = ch * 8 + srow8;          // tile row 0..127
      int qg = sq ^ (gr & 7);           // swizzled source quad
      const ushort_t* ga = A + (size_t)(bm + gr) * K_DIM + kt + qg * 8;
      __builtin_amdgcn_global_load_lds(
          (const __attribute__((address_space(1))) void*)ga,
          (__attribute__((address_space(3))) void*)&As[ch * 512], 16, 0, 0);
      const ushort_t* gb = B + (size_t)(bn + gr) * K_DIM + kt + qg * 8;
      __builtin_amdgcn_global_load_lds(
          (const __attribute__((address_space(1))) void*)gb,
          (__attribute__((address_space(3))) void*)&Bs[ch * 512], 16, 0, 0);
    }
    __syncthreads();

    bf16x8_t af[2][4], bfr[2][4];
#pragma unroll
    for (int h = 0; h < 2; ++h) {
#pragma unroll
      for (int i = 0; i < 4; ++i) {
        int kq = h * 4 + quad;
        int ar = wrow * 64 + i * 16 + l16;
        af[h][i]  = *(const bf16x8_t*)&As[ar * BK + ((kq ^ (ar & 7)) * 8)];
        int br = wcol * 64 + i * 16 + l16;
        bfr[h][i] = *(const bf16x8_t*)&Bs[br * BK + ((kq ^ (br & 7)) * 8)];
      }
    }
#pragma unroll
    for (int h = 0; h < 2; ++h)
#pragma unroll
      for (int i = 0; i < 4; ++i)
#pragma unroll
        for (int j = 0; j < 4; ++j)
          acc[i][j] = __builtin_amdgcn_mfma_f32_16x16x32_bf16(af[h][i], bfr[h][j], acc[i][j], 0, 0, 0);
    __syncthreads();
  }

  // epilogue: C/D layout col = lane&15 (n side), row = quad*4 + reg (m side)
#pragma unroll
  for (int i = 0; i < 4; ++i) {
#pragma unroll
    for (int j = 0; j < 4; ++j) {
      int col = bn + wcol * 64 + j * 16 + l16;
#pragma unroll
      for (int r = 0; r < 4; ++r) {
        int row = bm + wrow * 64 + i * 16 + quad * 4 + r;
        dst[(size_t)row * N_DIM + col] = acc[i][j][r];
      }
    }
  }
}

// ---------------------------------------------------------------------------
// Kernel 4: out += partial (float4)
// ---------------------------------------------------------------------------
__global__ __launch_bounds__(256) void add_partial(float* __restrict__ out,
                                                   const float* __restrict__ part) {
  int i = blockIdx.x * 256 + threadIdx.x;
  float4 a = ((const float4*)out)[i];
  float4 b = ((const float4*)part)[i];
  a.x += b.x; a.y += b.y; a.z += b.z; a.w += b.w;
  ((float4*)out)[i] = a;
}

extern "C" void kernel_launch(void* const* d_in, const int* in_sizes, int n_in,
                              void* d_out, int out_size, void* d_ws, size_t ws_size,
                              hipStream_t stream) {
  const float* x        = (const float*)d_in[0];   // [2,512,4096]
  const float* weight   = (const float*)d_in[1];   // [4096,4096]
  const float* spectrum = (const float*)d_in[2];   // [10000]
  const int*   indices  = (const int*)d_in[3];     // [2,10000]
  float* out = (float*)d_out;                      // [2,512,4096]

  char* ws = (char*)d_ws;
  const size_t WB_BYTES   = (size_t)N_DIM * K_DIM * 2;   // 32 MB
  const size_t XB_BYTES   = (size_t)M_DIM * K_DIM * 2;   //  8 MB
  const size_t PART_BYTES = (size_t)M_DIM * N_DIM * 4;   // 16 MB

  ushort_t* wb = (ushort_t*)ws;
  ushort_t* xb = (ushort_t*)(ws + WB_BYTES);
  const bool split = ws_size >= WB_BYTES + XB_BYTES + PART_BYTES;
  float* part = (float*)(ws + WB_BYTES + XB_BYTES);

  build_w3<<<dim3(K_DIM / 64, N_DIM / 256), 256, 0, stream>>>(weight, spectrum, indices, wb);
  cvt_x<<<(M_DIM * K_DIM / 4) / 256, 256, 0, stream>>>(x, xb);

  if (split) {
    gemm_bt<<<dim3(N_DIM / 128, M_DIM / 128, 2), 256, 0, stream>>>(xb, wb, out, part, K_DIM / 2);
    add_partial<<<(M_DIM * N_DIM / 4) / 256, 256, 0, stream>>>(out, part);
  } else {
    gemm_bt<<<dim3(N_DIM / 128, M_DIM / 128, 1), 256, 0, stream>>>(xb, wb, out, out, K_DIM);
  }
}